// Round 7
// baseline (525.341 us; speedup 1.0000x reference)
//
#include <hip/hip_runtime.h>

#define N_NODES 100000
#define N_EDGES 1600000

// ---------------------------------------------------------------------------
__global__ void hist_kernel(const int* __restrict__ dst, int* __restrict__ counts, int E) {
    int e = blockIdx.x * blockDim.x + threadIdx.x;
    if (e < E) atomicAdd(&counts[dst[e]], 1);
}

__global__ void dinv_kernel(const int* __restrict__ counts, float* __restrict__ dinv, int n) {
    int i = blockIdx.x * blockDim.x + threadIdx.x;
    if (i < n) dinv[i] = rsqrtf((float)counts[i] + 1.0f);
}

// --- 3-kernel exclusive scan of counts[n] -> rowptr[n] ----------------------
__global__ void scan1_kernel(const int* __restrict__ counts, int* __restrict__ rowptr,
                             int* __restrict__ bsums, int n) {
    __shared__ int s[256];
    int i = blockIdx.x * 256 + threadIdx.x;
    int v = (i < n) ? counts[i] : 0;
    s[threadIdx.x] = v;
    __syncthreads();
    for (int off = 1; off < 256; off <<= 1) {
        int t = (threadIdx.x >= off) ? s[threadIdx.x - off] : 0;
        __syncthreads();
        s[threadIdx.x] += t;
        __syncthreads();
    }
    if (i < n) rowptr[i] = s[threadIdx.x] - v;
    if (threadIdx.x == 255) bsums[blockIdx.x] = s[255];
}

__global__ void scan2_kernel(int* __restrict__ bsums, int nb) {
    __shared__ int s[512];
    int t = threadIdx.x;
    int v = (t < nb) ? bsums[t] : 0;
    s[t] = v;
    __syncthreads();
    for (int off = 1; off < 512; off <<= 1) {
        int u = (t >= off) ? s[t - off] : 0;
        __syncthreads();
        s[t] += u;
        __syncthreads();
    }
    if (t < nb) bsums[t] = s[t] - v;
}

__global__ void scan3_kernel(int* __restrict__ rowptr, const int* __restrict__ bsums, int n) {
    int i = blockIdx.x * 256 + threadIdx.x;
    if (i < n) rowptr[i] += bsums[blockIdx.x];
}

// --- scatter: pure permutation (weights folded into GEMM epilogue) ----------
// After this kernel rowptr[d] == row END of d. Row-internal order is RACY.
__global__ void scatter_kernel(const int* __restrict__ src, const int* __restrict__ dst,
                               int* __restrict__ rowptr, int* __restrict__ eidx, int E) {
    int e = blockIdx.x * blockDim.x + threadIdx.x;
    if (e >= E) return;
    int d = dst[e];
    int pos = atomicAdd(&rowptr[d], 1);
    eidx[pos] = src[e];
}

// --- determinism fix: sort each row ascending by src so fp sum order is a
// pure function of the inputs (atomic scatter order no longer observable).
// One thread per node; insertion sort; rows ~Poisson(16), eidx L2-resident.
__global__ void sortrow_kernel(const int* __restrict__ rowend, int* __restrict__ eidx, int n) {
    int g = blockIdx.x * blockDim.x + threadIdx.x;
    if (g >= n) return;
    int start = (g == 0) ? 0 : rowend[g - 1];
    int end = rowend[g];
    for (int i = start + 1; i < end; i++) {
        int key = eidx[i];
        int j = i - 1;
        while (j >= start && eidx[j] > key) {
            eidx[j + 1] = eidx[j];
            j--;
        }
        eidx[j + 1] = key;
    }
}

// ---------------------------------------------------------------------------
// LDS-tiled GEMM, 4x4 register blocking, epilogue scales row r by dinv[r].
// __launch_bounds__(256,2) + unroll 2: no spill (round-4 lesson).
template <int FIN, int FOUT>
__global__ __launch_bounds__(256, 2)
void gemm_tiled(const float* __restrict__ in, const float* __restrict__ W,
                const float* __restrict__ dinv, float* __restrict__ out, int n) {
    constexpr int CG = FOUT / 4;
    constexpr int RG = 256 / CG;
    constexpr int TR = RG * 4;
    constexpr int LDA = FIN + 4;
    __shared__ float sIn[TR * LDA];
    __shared__ float sW[FIN * FOUT];

    for (int i = threadIdx.x; i < FIN * FOUT / 4; i += 256)
        ((float4*)sW)[i] = ((const float4*)W)[i];

    int r0 = blockIdx.x * TR;
    for (int i = threadIdx.x; i < TR * FIN / 4; i += 256) {
        int rr = i / (FIN / 4);
        int cc = i % (FIN / 4);
        int gr = r0 + rr;
        float4 v = (gr < n) ? ((const float4*)in)[(size_t)gr * (FIN / 4) + cc]
                            : make_float4(0.f, 0.f, 0.f, 0.f);
        *(float4*)&sIn[rr * LDA + cc * 4] = v;
    }
    __syncthreads();

    int tc = threadIdx.x % CG;
    int tr = threadIdx.x / CG;
    int rbase = tr * 4, cbase = tc * 4;
    float acc[4][4] = {};

#pragma unroll 2
    for (int k = 0; k < FIN; k += 4) {
        float4 a[4], b[4];
#pragma unroll
        for (int i = 0; i < 4; i++) a[i] = *(float4*)&sIn[(rbase + i) * LDA + k];
#pragma unroll
        for (int kk = 0; kk < 4; kk++) b[kk] = *(float4*)&sW[(k + kk) * FOUT + cbase];
#pragma unroll
        for (int i = 0; i < 4; i++) {
            acc[i][0] += a[i].x * b[0].x + a[i].y * b[1].x + a[i].z * b[2].x + a[i].w * b[3].x;
            acc[i][1] += a[i].x * b[0].y + a[i].y * b[1].y + a[i].z * b[2].y + a[i].w * b[3].y;
            acc[i][2] += a[i].x * b[0].z + a[i].y * b[1].z + a[i].z * b[2].z + a[i].w * b[3].z;
            acc[i][3] += a[i].x * b[0].w + a[i].y * b[1].w + a[i].z * b[2].w + a[i].w * b[3].w;
        }
    }

#pragma unroll
    for (int i = 0; i < 4; i++) {
        int gr = r0 + rbase + i;
        if (gr < n) {
            float dv = dinv[gr];
            *(float4*)&out[(size_t)gr * FOUT + cbase] =
                make_float4(dv * acc[i][0], dv * acc[i][1], dv * acc[i][2], dv * acc[i][3]);
        }
    }
}

// simple GEMM for the tiny 32->2 layer, same dinv-scaled epilogue
template <int FIN, int FOUT>
__global__ void gemm_kernel(const float* __restrict__ in, const float* __restrict__ W,
                            const float* __restrict__ dinv, float* __restrict__ out, int n) {
    __shared__ float sW[FIN * FOUT];
    for (int i = threadIdx.x; i < FIN * FOUT; i += blockDim.x) sW[i] = W[i];
    __syncthreads();
    constexpr int ROWS = 256 / FOUT;
    int r = blockIdx.x * ROWS + threadIdx.x / FOUT;
    int c = threadIdx.x % FOUT;
    if (r >= n) return;
    float acc = 0.f;
#pragma unroll
    for (int k = 0; k < FIN; k++) acc += in[r * FIN + k] * sW[k * FOUT + c];
    out[r * FOUT + c] = dinv[r] * acc;
}

// ---------------------------------------------------------------------------
// Gather-side aggregation over dinv-prescaled features h':
//   out[g] = (relu?)( dinv[g] * (sum_{s in nbrs} h'[s] + h'[g]) + b )
// Zero atomics, deterministic (rows sorted), 8 gather chains in flight.
template <int F, bool RELU>
__global__ void agg_kernel(const int* __restrict__ eidx, const int* __restrict__ rowend,
                           const float* __restrict__ dinv, const float* __restrict__ h,
                           const float* __restrict__ b, float* __restrict__ out, int n) {
    int g = (blockIdx.x * blockDim.x + threadIdx.x) / F;
    int lane = threadIdx.x % F;
    if (g >= n) return;
    int end = rowend[g];
    int j = (g == 0) ? 0 : rowend[g - 1];
    float di = dinv[g];
    float hs = h[(size_t)g * F + lane];

    float acc0 = 0.f, acc1 = 0.f, acc2 = 0.f, acc3 = 0.f;
    float acc4 = 0.f, acc5 = 0.f, acc6 = 0.f, acc7 = 0.f;
    for (; j + 8 <= end; j += 8) {
        int s0 = eidx[j];
        int s1 = eidx[j + 1];
        int s2 = eidx[j + 2];
        int s3 = eidx[j + 3];
        int s4 = eidx[j + 4];
        int s5 = eidx[j + 5];
        int s6 = eidx[j + 6];
        int s7 = eidx[j + 7];
        acc0 += h[(size_t)s0 * F + lane];
        acc1 += h[(size_t)s1 * F + lane];
        acc2 += h[(size_t)s2 * F + lane];
        acc3 += h[(size_t)s3 * F + lane];
        acc4 += h[(size_t)s4 * F + lane];
        acc5 += h[(size_t)s5 * F + lane];
        acc6 += h[(size_t)s6 * F + lane];
        acc7 += h[(size_t)s7 * F + lane];
    }
    for (; j + 2 <= end; j += 2) {
        int s0 = eidx[j];
        int s1 = eidx[j + 1];
        acc0 += h[(size_t)s0 * F + lane];
        acc1 += h[(size_t)s1 * F + lane];
    }
    if (j < end) {
        acc2 += h[(size_t)eidx[j] * F + lane];
    }
    float acc = ((acc0 + acc1) + (acc2 + acc3)) + ((acc4 + acc5) + (acc6 + acc7));
    float v = di * (acc + hs) + b[lane];
    out[(size_t)g * F + lane] = RELU ? fmaxf(v, 0.f) : v;
}

// ---------------------------------------------------------------------------
extern "C" void kernel_launch(void* const* d_in, const int* in_sizes, int n_in,
                              void* d_out, int out_size, void* d_ws, size_t ws_size,
                              hipStream_t stream) {
    const float* x  = (const float*)d_in[0];
    const int* ei   = (const int*)d_in[1];
    const float* W1 = (const float*)d_in[2];
    const float* b1 = (const float*)d_in[3];
    const float* W2 = (const float*)d_in[4];
    const float* b2 = (const float*)d_in[5];
    const float* W3 = (const float*)d_in[6];
    const float* b3 = (const float*)d_in[7];
    float* out = (float*)d_out;

    const int N = N_NODES;
    const int E = N_EDGES;
    const int* src = ei;
    const int* dst = ei + E;

    char* p = (char*)d_ws;
    int*   counts = (int*)p;              p += ((size_t)N * 4 + 15) / 16 * 16;
    int*   rowptr = (int*)p;              p += ((size_t)N * 4 + 15) / 16 * 16;
    int*   bsums  = (int*)p;              p += 512 * 4;
    float* dinv   = (float*)p;            p += ((size_t)N * 4 + 15) / 16 * 16;
    int*   eidx   = (int*)p;              p += (size_t)E * 4;
    float* A      = (float*)p;            p += (size_t)N * 64 * 4;
    float* B      = (float*)p;

    const int T = 256;
    const int NB = (N + 255) / 256;

    // --- build CSR + dinv (deterministic: rows sorted after racy scatter) ---
    hipMemsetAsync(counts, 0, (size_t)N * sizeof(int), stream);
    hist_kernel<<<(E + T - 1) / T, T, 0, stream>>>(dst, counts, E);
    dinv_kernel<<<NB, T, 0, stream>>>(counts, dinv, N);
    scan1_kernel<<<NB, T, 0, stream>>>(counts, rowptr, bsums, N);
    scan2_kernel<<<1, 512, 0, stream>>>(bsums, NB);
    scan3_kernel<<<NB, T, 0, stream>>>(rowptr, bsums, N);
    scatter_kernel<<<(E + T - 1) / T, T, 0, stream>>>(src, dst, rowptr, eidx, E);
    sortrow_kernel<<<NB, T, 0, stream>>>(rowptr, eidx, N);

    // --- layer 1: h1' = dinv * (x @ W1) -> A; aggregate+relu -> B ---
    gemm_tiled<64, 64><<<(N + 63) / 64, T, 0, stream>>>(x, W1, dinv, A, N);
    agg_kernel<64, true><<<(N * 64 + T - 1) / T, T, 0, stream>>>(eidx, rowptr, dinv, A, b1, B, N);

    // --- layer 2 ---
    gemm_tiled<64, 32><<<(N + 127) / 128, T, 0, stream>>>(B, W2, dinv, A, N);
    agg_kernel<32, true><<<(N * 32 + T - 1) / T, T, 0, stream>>>(eidx, rowptr, dinv, A, b2, B, N);

    // --- layer 3 ---
    gemm_kernel<32, 2><<<(N + 127) / 128, T, 0, stream>>>(B, W3, dinv, A, N);
    agg_kernel<2, false><<<(N * 2 + T - 1) / T, T, 0, stream>>>(eidx, rowptr, dinv, A, b3, out, N);
}

// Round 8
// 469.623 us; speedup vs baseline: 1.1186x; 1.1186x over previous
//
#include <hip/hip_runtime.h>

#define N_NODES 100000
#define N_EDGES 1600000

// ---------------------------------------------------------------------------
__global__ void hist_kernel(const int* __restrict__ dst, int* __restrict__ counts, int E) {
    int e = blockIdx.x * blockDim.x + threadIdx.x;
    if (e < E) atomicAdd(&counts[dst[e]], 1);
}

__global__ void dinv_kernel(const int* __restrict__ counts, float* __restrict__ dinv, int n) {
    int i = blockIdx.x * blockDim.x + threadIdx.x;
    if (i < n) dinv[i] = rsqrtf((float)counts[i] + 1.0f);
}

// --- 3-kernel exclusive scan of counts[n] -> rowptr[n] ----------------------
__global__ void scan1_kernel(const int* __restrict__ counts, int* __restrict__ rowptr,
                             int* __restrict__ bsums, int n) {
    __shared__ int s[256];
    int i = blockIdx.x * 256 + threadIdx.x;
    int v = (i < n) ? counts[i] : 0;
    s[threadIdx.x] = v;
    __syncthreads();
    for (int off = 1; off < 256; off <<= 1) {
        int t = (threadIdx.x >= off) ? s[threadIdx.x - off] : 0;
        __syncthreads();
        s[threadIdx.x] += t;
        __syncthreads();
    }
    if (i < n) rowptr[i] = s[threadIdx.x] - v;
    if (threadIdx.x == 255) bsums[blockIdx.x] = s[255];
}

__global__ void scan2_kernel(int* __restrict__ bsums, int nb) {
    __shared__ int s[512];
    int t = threadIdx.x;
    int v = (t < nb) ? bsums[t] : 0;
    s[t] = v;
    __syncthreads();
    for (int off = 1; off < 512; off <<= 1) {
        int u = (t >= off) ? s[t - off] : 0;
        __syncthreads();
        s[t] += u;
        __syncthreads();
    }
    if (t < nb) bsums[t] = s[t] - v;
}

__global__ void scan3_kernel(int* __restrict__ rowptr, const int* __restrict__ bsums, int n) {
    int i = blockIdx.x * 256 + threadIdx.x;
    if (i < n) rowptr[i] += bsums[blockIdx.x];
}

// --- scatter: pure permutation; 4 edges/thread for 4 independent
// load->atomic->store chains (round-7 was latency-bound at 1 chain/thread).
// After this kernel rowptr[d] == row END of d. Row-internal order is RACY
// (made canonical by sortrow_wave below).
__global__ void scatter_kernel(const int* __restrict__ src, const int* __restrict__ dst,
                               int* __restrict__ rowptr, int* __restrict__ eidx, int E) {
    int base = blockIdx.x * 1024 + threadIdx.x;
#pragma unroll
    for (int u = 0; u < 4; u++) {
        int e = base + u * 256;
        if (e < E) {
            int d = dst[e];
            int s = src[e];
            int pos = atomicAdd(&rowptr[d], 1);
            eidx[pos] = s;
        }
    }
}

// --- determinism: canonicalize each row (sort ascending). One WAVE per row,
// 21-stage bitonic network via shfl_xor over 64 lanes (deg ~Poisson(16),
// max ~40 << 64; serial fallback for deg > 64 just in case).
__global__ void sortrow_wave(const int* __restrict__ rowend, int* __restrict__ eidx, int n) {
    int g = (blockIdx.x * blockDim.x + threadIdx.x) >> 6;   // wave id = row
    int lane = threadIdx.x & 63;
    if (g >= n) return;
    int start = (g == 0) ? 0 : rowend[g - 1];
    int end = rowend[g];
    int len = end - start;
    if (len <= 1) return;

    if (len <= 64) {
        int v = (lane < len) ? eidx[start + lane] : 0x7fffffff;
#pragma unroll
        for (int k = 2; k <= 64; k <<= 1) {
#pragma unroll
            for (int j = k >> 1; j > 0; j >>= 1) {
                int partner = __shfl_xor(v, j, 64);
                bool up = ((lane & k) == 0);
                bool keepMin = (((lane & j) == 0) == up);
                int mn = min(v, partner), mx = max(v, partner);
                v = keepMin ? mn : mx;
            }
        }
        if (lane < len) eidx[start + lane] = v;
    } else if (lane == 0) {
        for (int i = start + 1; i < end; i++) {
            int key = eidx[i];
            int j = i - 1;
            while (j >= start && eidx[j] > key) { eidx[j + 1] = eidx[j]; j--; }
            eidx[j + 1] = key;
        }
    }
}

// ---------------------------------------------------------------------------
// LDS-tiled GEMM, 4x4 register blocking, epilogue scales row r by dinv[r].
// __launch_bounds__(256,2) + unroll 2: no spill (round-4 lesson).
template <int FIN, int FOUT>
__global__ __launch_bounds__(256, 2)
void gemm_tiled(const float* __restrict__ in, const float* __restrict__ W,
                const float* __restrict__ dinv, float* __restrict__ out, int n) {
    constexpr int CG = FOUT / 4;
    constexpr int RG = 256 / CG;
    constexpr int TR = RG * 4;
    constexpr int LDA = FIN + 4;
    __shared__ float sIn[TR * LDA];
    __shared__ float sW[FIN * FOUT];

    for (int i = threadIdx.x; i < FIN * FOUT / 4; i += 256)
        ((float4*)sW)[i] = ((const float4*)W)[i];

    int r0 = blockIdx.x * TR;
    for (int i = threadIdx.x; i < TR * FIN / 4; i += 256) {
        int rr = i / (FIN / 4);
        int cc = i % (FIN / 4);
        int gr = r0 + rr;
        float4 v = (gr < n) ? ((const float4*)in)[(size_t)gr * (FIN / 4) + cc]
                            : make_float4(0.f, 0.f, 0.f, 0.f);
        *(float4*)&sIn[rr * LDA + cc * 4] = v;
    }
    __syncthreads();

    int tc = threadIdx.x % CG;
    int tr = threadIdx.x / CG;
    int rbase = tr * 4, cbase = tc * 4;
    float acc[4][4] = {};

#pragma unroll 2
    for (int k = 0; k < FIN; k += 4) {
        float4 a[4], b[4];
#pragma unroll
        for (int i = 0; i < 4; i++) a[i] = *(float4*)&sIn[(rbase + i) * LDA + k];
#pragma unroll
        for (int kk = 0; kk < 4; kk++) b[kk] = *(float4*)&sW[(k + kk) * FOUT + cbase];
#pragma unroll
        for (int i = 0; i < 4; i++) {
            acc[i][0] += a[i].x * b[0].x + a[i].y * b[1].x + a[i].z * b[2].x + a[i].w * b[3].x;
            acc[i][1] += a[i].x * b[0].y + a[i].y * b[1].y + a[i].z * b[2].y + a[i].w * b[3].y;
            acc[i][2] += a[i].x * b[0].z + a[i].y * b[1].z + a[i].z * b[2].z + a[i].w * b[3].z;
            acc[i][3] += a[i].x * b[0].w + a[i].y * b[1].w + a[i].z * b[2].w + a[i].w * b[3].w;
        }
    }

#pragma unroll
    for (int i = 0; i < 4; i++) {
        int gr = r0 + rbase + i;
        if (gr < n) {
            float dv = dinv[gr];
            *(float4*)&out[(size_t)gr * FOUT + cbase] =
                make_float4(dv * acc[i][0], dv * acc[i][1], dv * acc[i][2], dv * acc[i][3]);
        }
    }
}

// simple GEMM for the tiny 32->2 layer, same dinv-scaled epilogue
template <int FIN, int FOUT>
__global__ void gemm_kernel(const float* __restrict__ in, const float* __restrict__ W,
                            const float* __restrict__ dinv, float* __restrict__ out, int n) {
    __shared__ float sW[FIN * FOUT];
    for (int i = threadIdx.x; i < FIN * FOUT; i += blockDim.x) sW[i] = W[i];
    __syncthreads();
    constexpr int ROWS = 256 / FOUT;
    int r = blockIdx.x * ROWS + threadIdx.x / FOUT;
    int c = threadIdx.x % FOUT;
    if (r >= n) return;
    float acc = 0.f;
#pragma unroll
    for (int k = 0; k < FIN; k++) acc += in[r * FIN + k] * sW[k * FOUT + c];
    out[r * FOUT + c] = dinv[r] * acc;
}

// ---------------------------------------------------------------------------
// Gather-side aggregation over dinv-prescaled features h':
//   out[g] = (relu?)( dinv[g] * (sum_{s in nbrs} h'[s] + h'[g]) + b )
// Zero atomics, deterministic (rows sorted), 8 gather chains in flight.
template <int F, bool RELU>
__global__ void agg_kernel(const int* __restrict__ eidx, const int* __restrict__ rowend,
                           const float* __restrict__ dinv, const float* __restrict__ h,
                           const float* __restrict__ b, float* __restrict__ out, int n) {
    int g = (blockIdx.x * blockDim.x + threadIdx.x) / F;
    int lane = threadIdx.x % F;
    if (g >= n) return;
    int end = rowend[g];
    int j = (g == 0) ? 0 : rowend[g - 1];
    float di = dinv[g];
    float hs = h[(size_t)g * F + lane];

    float acc0 = 0.f, acc1 = 0.f, acc2 = 0.f, acc3 = 0.f;
    float acc4 = 0.f, acc5 = 0.f, acc6 = 0.f, acc7 = 0.f;
    for (; j + 8 <= end; j += 8) {
        int s0 = eidx[j];
        int s1 = eidx[j + 1];
        int s2 = eidx[j + 2];
        int s3 = eidx[j + 3];
        int s4 = eidx[j + 4];
        int s5 = eidx[j + 5];
        int s6 = eidx[j + 6];
        int s7 = eidx[j + 7];
        acc0 += h[(size_t)s0 * F + lane];
        acc1 += h[(size_t)s1 * F + lane];
        acc2 += h[(size_t)s2 * F + lane];
        acc3 += h[(size_t)s3 * F + lane];
        acc4 += h[(size_t)s4 * F + lane];
        acc5 += h[(size_t)s5 * F + lane];
        acc6 += h[(size_t)s6 * F + lane];
        acc7 += h[(size_t)s7 * F + lane];
    }
    for (; j + 2 <= end; j += 2) {
        int s0 = eidx[j];
        int s1 = eidx[j + 1];
        acc0 += h[(size_t)s0 * F + lane];
        acc1 += h[(size_t)s1 * F + lane];
    }
    if (j < end) {
        acc2 += h[(size_t)eidx[j] * F + lane];
    }
    float acc = ((acc0 + acc1) + (acc2 + acc3)) + ((acc4 + acc5) + (acc6 + acc7));
    float v = di * (acc + hs) + b[lane];
    out[(size_t)g * F + lane] = RELU ? fmaxf(v, 0.f) : v;
}

// ---------------------------------------------------------------------------
extern "C" void kernel_launch(void* const* d_in, const int* in_sizes, int n_in,
                              void* d_out, int out_size, void* d_ws, size_t ws_size,
                              hipStream_t stream) {
    const float* x  = (const float*)d_in[0];
    const int* ei   = (const int*)d_in[1];
    const float* W1 = (const float*)d_in[2];
    const float* b1 = (const float*)d_in[3];
    const float* W2 = (const float*)d_in[4];
    const float* b2 = (const float*)d_in[5];
    const float* W3 = (const float*)d_in[6];
    const float* b3 = (const float*)d_in[7];
    float* out = (float*)d_out;

    const int N = N_NODES;
    const int E = N_EDGES;
    const int* src = ei;
    const int* dst = ei + E;

    char* p = (char*)d_ws;
    int*   counts = (int*)p;              p += ((size_t)N * 4 + 15) / 16 * 16;
    int*   rowptr = (int*)p;              p += ((size_t)N * 4 + 15) / 16 * 16;
    int*   bsums  = (int*)p;              p += 512 * 4;
    float* dinv   = (float*)p;            p += ((size_t)N * 4 + 15) / 16 * 16;
    int*   eidx   = (int*)p;              p += (size_t)E * 4;
    float* A      = (float*)p;            p += (size_t)N * 64 * 4;
    float* B      = (float*)p;

    const int T = 256;
    const int NB = (N + 255) / 256;

    // --- build CSR + dinv (deterministic: rows canonicalized after racy scatter) ---
    hipMemsetAsync(counts, 0, (size_t)N * sizeof(int), stream);
    hist_kernel<<<(E + T - 1) / T, T, 0, stream>>>(dst, counts, E);
    dinv_kernel<<<NB, T, 0, stream>>>(counts, dinv, N);
    scan1_kernel<<<NB, T, 0, stream>>>(counts, rowptr, bsums, N);
    scan2_kernel<<<1, 512, 0, stream>>>(bsums, NB);
    scan3_kernel<<<NB, T, 0, stream>>>(rowptr, bsums, N);
    scatter_kernel<<<(E + 1023) / 1024, T, 0, stream>>>(src, dst, rowptr, eidx, E);
    sortrow_wave<<<(N * 64 + T - 1) / T, T, 0, stream>>>(rowptr, eidx, N);

    // --- layer 1: h1' = dinv * (x @ W1) -> A; aggregate+relu -> B ---
    gemm_tiled<64, 64><<<(N + 63) / 64, T, 0, stream>>>(x, W1, dinv, A, N);
    agg_kernel<64, true><<<(N * 64 + T - 1) / T, T, 0, stream>>>(eidx, rowptr, dinv, A, b1, B, N);

    // --- layer 2 ---
    gemm_tiled<64, 32><<<(N + 127) / 128, T, 0, stream>>>(B, W2, dinv, A, N);
    agg_kernel<32, true><<<(N * 32 + T - 1) / T, T, 0, stream>>>(eidx, rowptr, dinv, A, b2, B, N);

    // --- layer 3 ---
    gemm_kernel<32, 2><<<(N + 127) / 128, T, 0, stream>>>(B, W3, dinv, A, N);
    agg_kernel<2, false><<<(N * 2 + T - 1) / T, T, 0, stream>>>(eidx, rowptr, dinv, A, b3, out, N);
}

// Round 9
// 417.417 us; speedup vs baseline: 1.2586x; 1.1251x over previous
//
#include <hip/hip_runtime.h>

#define N_NODES 100000
#define N_EDGES 1600000
#define BSHIFT 9
#define NBUCK ((N_NODES + 511) / 512)   // 196 coarse buckets of 512 nodes

// ---------------------------------------------------------------------------
__global__ void hist_kernel(const int* __restrict__ dst, int* __restrict__ counts, int E) {
    int e = blockIdx.x * blockDim.x + threadIdx.x;
    if (e < E) atomicAdd(&counts[dst[e]], 1);
}

__global__ void dinv_kernel(const int* __restrict__ counts, float* __restrict__ dinv, int n) {
    int i = blockIdx.x * blockDim.x + threadIdx.x;
    if (i < n) dinv[i] = rsqrtf((float)counts[i] + 1.0f);
}

// --- 3-kernel exclusive scan of counts[n] -> rowptr[n] ----------------------
__global__ void scan1_kernel(const int* __restrict__ counts, int* __restrict__ rowptr,
                             int* __restrict__ bsums, int n) {
    __shared__ int s[256];
    int i = blockIdx.x * 256 + threadIdx.x;
    int v = (i < n) ? counts[i] : 0;
    s[threadIdx.x] = v;
    __syncthreads();
    for (int off = 1; off < 256; off <<= 1) {
        int t = (threadIdx.x >= off) ? s[threadIdx.x - off] : 0;
        __syncthreads();
        s[threadIdx.x] += t;
        __syncthreads();
    }
    if (i < n) rowptr[i] = s[threadIdx.x] - v;
    if (threadIdx.x == 255) bsums[blockIdx.x] = s[255];
}

__global__ void scan2_kernel(int* __restrict__ bsums, int nb) {
    __shared__ int s[512];
    int t = threadIdx.x;
    int v = (t < nb) ? bsums[t] : 0;
    s[t] = v;
    __syncthreads();
    for (int off = 1; off < 512; off <<= 1) {
        int u = (t >= off) ? s[t - off] : 0;
        __syncthreads();
        s[t] += u;
        __syncthreads();
    }
    if (t < nb) bsums[t] = s[t] - v;
}

__global__ void scan3_kernel(int* __restrict__ rowptr, const int* __restrict__ bsums, int n) {
    int i = blockIdx.x * 256 + threadIdx.x;
    if (i < n) rowptr[i] += bsums[blockIdx.x];
}

// --- gcursor[b] = bucket b's start in bbuf (== eidx coords); rowptr[N] = E ---
__global__ void bucket_init_kernel(const int* __restrict__ rowptr, int* __restrict__ gcursor,
                                   int* __restrict__ rowptrN, int E) {
    int b = blockIdx.x * blockDim.x + threadIdx.x;
    if (b < NBUCK) gcursor[b] = rowptr[b << BSHIFT];
    if (b == 0) *rowptrN = E;
}

// --- phase 1: bucket edges by dst>>9. Per-block LDS hist -> one global
// atomicAdd per (block,bucket) reserves a PRIVATE contiguous subrange ->
// block-private lines (single XCD) instead of the 106 MB random-scatter wall.
__global__ void bucket1_kernel(const int* __restrict__ src, const int* __restrict__ dst,
                               int* __restrict__ gcursor, int2* __restrict__ bbuf, int E) {
    __shared__ int hcnt[NBUCK];
    __shared__ int hbase[NBUCK];
    int t = threadIdx.x;
    for (int i = t; i < NBUCK; i += 256) hcnt[i] = 0;
    __syncthreads();
    int e0 = blockIdx.x * 2048 + t;
    int ss[8], dd[8];
#pragma unroll
    for (int u = 0; u < 8; u++) {
        int e = e0 + u * 256;
        if (e < E) {
            ss[u] = src[e];
            dd[u] = dst[e];
            atomicAdd(&hcnt[dd[u] >> BSHIFT], 1);
        } else {
            dd[u] = -1;
        }
    }
    __syncthreads();
    for (int i = t; i < NBUCK; i += 256) {
        int c = hcnt[i];
        hbase[i] = c ? atomicAdd(&gcursor[i], c) : 0;
        hcnt[i] = 0;   // reuse as local cursor
    }
    __syncthreads();
#pragma unroll
    for (int u = 0; u < 8; u++) {
        if (dd[u] >= 0) {
            int bk = dd[u] >> BSHIFT;
            int r = atomicAdd(&hcnt[bk], 1);
            bbuf[hbase[bk] + r] = make_int2(ss[u], dd[u]);
        }
    }
}

// --- phase 2: one block per bucket; LDS per-node cursors; writes land in a
// ~65 KB block-private eidx range (one XCD -> full line merging in L2).
__global__ void bucket2_kernel(const int2* __restrict__ bbuf, const int* __restrict__ rowptr,
                               int* __restrict__ eidx, int N, int E) {
    int b = blockIdx.x;
    int base_node = b << BSHIFT;
    int nn = min(512, N - base_node);
    __shared__ int cur[512];
    for (int i = threadIdx.x; i < nn; i += 256) cur[i] = rowptr[base_node + i];
    __syncthreads();
    int rstart = rowptr[base_node];
    int rend = rowptr[min(base_node + 512, N)];   // rowptr[N] == E
    for (int j = rstart + threadIdx.x; j < rend; j += 256) {
        int2 e = bbuf[j];
        int pos = atomicAdd(&cur[e.y - base_node], 1);
        eidx[pos] = e.x;
    }
}

// --- determinism: canonicalize each row (sort ascending). One WAVE per row,
// bitonic via shfl_xor (deg ~Poisson(16), max << 64; serial fallback).
__global__ void sortrow_wave(const int* __restrict__ rowptr, int* __restrict__ eidx, int n) {
    int g = (blockIdx.x * blockDim.x + threadIdx.x) >> 6;
    int lane = threadIdx.x & 63;
    if (g >= n) return;
    int start = rowptr[g];
    int end = rowptr[g + 1];
    int len = end - start;
    if (len <= 1) return;

    if (len <= 64) {
        int v = (lane < len) ? eidx[start + lane] : 0x7fffffff;
#pragma unroll
        for (int k = 2; k <= 64; k <<= 1) {
#pragma unroll
            for (int j = k >> 1; j > 0; j >>= 1) {
                int partner = __shfl_xor(v, j, 64);
                bool up = ((lane & k) == 0);
                bool keepMin = (((lane & j) == 0) == up);
                int mn = min(v, partner), mx = max(v, partner);
                v = keepMin ? mn : mx;
            }
        }
        if (lane < len) eidx[start + lane] = v;
    } else if (lane == 0) {
        for (int i = start + 1; i < end; i++) {
            int key = eidx[i];
            int j = i - 1;
            while (j >= start && eidx[j] > key) { eidx[j + 1] = eidx[j]; j--; }
            eidx[j + 1] = key;
        }
    }
}

// ---------------------------------------------------------------------------
// LDS-tiled GEMM, 4x4 register blocking, epilogue scales row r by dinv[r].
// __launch_bounds__(256,2) + unroll 2: no spill (round-4 lesson).
template <int FIN, int FOUT>
__global__ __launch_bounds__(256, 2)
void gemm_tiled(const float* __restrict__ in, const float* __restrict__ W,
                const float* __restrict__ dinv, float* __restrict__ out, int n) {
    constexpr int CG = FOUT / 4;
    constexpr int RG = 256 / CG;
    constexpr int TR = RG * 4;
    constexpr int LDA = FIN + 4;
    __shared__ float sIn[TR * LDA];
    __shared__ float sW[FIN * FOUT];

    for (int i = threadIdx.x; i < FIN * FOUT / 4; i += 256)
        ((float4*)sW)[i] = ((const float4*)W)[i];

    int r0 = blockIdx.x * TR;
    for (int i = threadIdx.x; i < TR * FIN / 4; i += 256) {
        int rr = i / (FIN / 4);
        int cc = i % (FIN / 4);
        int gr = r0 + rr;
        float4 v = (gr < n) ? ((const float4*)in)[(size_t)gr * (FIN / 4) + cc]
                            : make_float4(0.f, 0.f, 0.f, 0.f);
        *(float4*)&sIn[rr * LDA + cc * 4] = v;
    }
    __syncthreads();

    int tc = threadIdx.x % CG;
    int tr = threadIdx.x / CG;
    int rbase = tr * 4, cbase = tc * 4;
    float acc[4][4] = {};

#pragma unroll 2
    for (int k = 0; k < FIN; k += 4) {
        float4 a[4], b[4];
#pragma unroll
        for (int i = 0; i < 4; i++) a[i] = *(float4*)&sIn[(rbase + i) * LDA + k];
#pragma unroll
        for (int kk = 0; kk < 4; kk++) b[kk] = *(float4*)&sW[(k + kk) * FOUT + cbase];
#pragma unroll
        for (int i = 0; i < 4; i++) {
            acc[i][0] += a[i].x * b[0].x + a[i].y * b[1].x + a[i].z * b[2].x + a[i].w * b[3].x;
            acc[i][1] += a[i].x * b[0].y + a[i].y * b[1].y + a[i].z * b[2].y + a[i].w * b[3].y;
            acc[i][2] += a[i].x * b[0].z + a[i].y * b[1].z + a[i].z * b[2].z + a[i].w * b[3].z;
            acc[i][3] += a[i].x * b[0].w + a[i].y * b[1].w + a[i].z * b[2].w + a[i].w * b[3].w;
        }
    }

#pragma unroll
    for (int i = 0; i < 4; i++) {
        int gr = r0 + rbase + i;
        if (gr < n) {
            float dv = dinv[gr];
            *(float4*)&out[(size_t)gr * FOUT + cbase] =
                make_float4(dv * acc[i][0], dv * acc[i][1], dv * acc[i][2], dv * acc[i][3]);
        }
    }
}

// simple GEMM for the tiny 32->2 layer, same dinv-scaled epilogue
template <int FIN, int FOUT>
__global__ void gemm_kernel(const float* __restrict__ in, const float* __restrict__ W,
                            const float* __restrict__ dinv, float* __restrict__ out, int n) {
    __shared__ float sW[FIN * FOUT];
    for (int i = threadIdx.x; i < FIN * FOUT; i += blockDim.x) sW[i] = W[i];
    __syncthreads();
    constexpr int ROWS = 256 / FOUT;
    int r = blockIdx.x * ROWS + threadIdx.x / FOUT;
    int c = threadIdx.x % FOUT;
    if (r >= n) return;
    float acc = 0.f;
#pragma unroll
    for (int k = 0; k < FIN; k++) acc += in[r * FIN + k] * sW[k * FOUT + c];
    out[r * FOUT + c] = dinv[r] * acc;
}

// ---------------------------------------------------------------------------
// Gather-side aggregation over dinv-prescaled features h':
//   out[g] = (relu?)( dinv[g] * (sum_{s in nbrs} h'[s] + h'[g]) + b )
// Zero atomics, deterministic (rows sorted), 8 gather chains in flight.
template <int F, bool RELU>
__global__ void agg_kernel(const int* __restrict__ eidx, const int* __restrict__ rowptr,
                           const float* __restrict__ dinv, const float* __restrict__ h,
                           const float* __restrict__ b, float* __restrict__ out, int n) {
    int g = (blockIdx.x * blockDim.x + threadIdx.x) / F;
    int lane = threadIdx.x % F;
    if (g >= n) return;
    int j = rowptr[g];
    int end = rowptr[g + 1];
    float di = dinv[g];
    float hs = h[(size_t)g * F + lane];

    float acc0 = 0.f, acc1 = 0.f, acc2 = 0.f, acc3 = 0.f;
    float acc4 = 0.f, acc5 = 0.f, acc6 = 0.f, acc7 = 0.f;
    for (; j + 8 <= end; j += 8) {
        int s0 = eidx[j];
        int s1 = eidx[j + 1];
        int s2 = eidx[j + 2];
        int s3 = eidx[j + 3];
        int s4 = eidx[j + 4];
        int s5 = eidx[j + 5];
        int s6 = eidx[j + 6];
        int s7 = eidx[j + 7];
        acc0 += h[(size_t)s0 * F + lane];
        acc1 += h[(size_t)s1 * F + lane];
        acc2 += h[(size_t)s2 * F + lane];
        acc3 += h[(size_t)s3 * F + lane];
        acc4 += h[(size_t)s4 * F + lane];
        acc5 += h[(size_t)s5 * F + lane];
        acc6 += h[(size_t)s6 * F + lane];
        acc7 += h[(size_t)s7 * F + lane];
    }
    for (; j + 2 <= end; j += 2) {
        int s0 = eidx[j];
        int s1 = eidx[j + 1];
        acc0 += h[(size_t)s0 * F + lane];
        acc1 += h[(size_t)s1 * F + lane];
    }
    if (j < end) {
        acc2 += h[(size_t)eidx[j] * F + lane];
    }
    float acc = ((acc0 + acc1) + (acc2 + acc3)) + ((acc4 + acc5) + (acc6 + acc7));
    float v = di * (acc + hs) + b[lane];
    out[(size_t)g * F + lane] = RELU ? fmaxf(v, 0.f) : v;
}

// ---------------------------------------------------------------------------
extern "C" void kernel_launch(void* const* d_in, const int* in_sizes, int n_in,
                              void* d_out, int out_size, void* d_ws, size_t ws_size,
                              hipStream_t stream) {
    const float* x  = (const float*)d_in[0];
    const int* ei   = (const int*)d_in[1];
    const float* W1 = (const float*)d_in[2];
    const float* b1 = (const float*)d_in[3];
    const float* W2 = (const float*)d_in[4];
    const float* b2 = (const float*)d_in[5];
    const float* W3 = (const float*)d_in[6];
    const float* b3 = (const float*)d_in[7];
    float* out = (float*)d_out;

    const int N = N_NODES;
    const int E = N_EDGES;
    const int* src = ei;
    const int* dst = ei + E;

    char* p = (char*)d_ws;
    int*   counts  = (int*)p;             p += ((size_t)N * 4 + 15) / 16 * 16;
    int*   rowptr  = (int*)p;             p += ((size_t)(N + 1) * 4 + 15) / 16 * 16;
    int*   bsums   = (int*)p;             p += 512 * 4;
    float* dinv    = (float*)p;           p += ((size_t)N * 4 + 15) / 16 * 16;
    int*   gcursor = (int*)p;             p += ((size_t)NBUCK * 4 + 15) / 16 * 16;
    int*   eidx    = (int*)p;             p += (size_t)E * 4;
    float* A       = (float*)p;           p += (size_t)N * 64 * 4;
    float* B       = (float*)p;
    int2*  bbuf    = (int2*)B;            // aliases B: dead until layer-1 agg

    const int T = 256;
    const int NB = (N + 255) / 256;

    // --- build CSR + dinv (bucketed 2-phase scatter; rows canonicalized) ---
    hipMemsetAsync(counts, 0, (size_t)N * sizeof(int), stream);
    hist_kernel<<<(E + T - 1) / T, T, 0, stream>>>(dst, counts, E);
    dinv_kernel<<<NB, T, 0, stream>>>(counts, dinv, N);
    scan1_kernel<<<NB, T, 0, stream>>>(counts, rowptr, bsums, N);
    scan2_kernel<<<1, 512, 0, stream>>>(bsums, NB);
    scan3_kernel<<<NB, T, 0, stream>>>(rowptr, bsums, N);
    bucket_init_kernel<<<(NBUCK + T - 1) / T, T, 0, stream>>>(rowptr, gcursor, rowptr + N, E);
    bucket1_kernel<<<(E + 2047) / 2048, T, 0, stream>>>(src, dst, gcursor, bbuf, E);
    bucket2_kernel<<<NBUCK, T, 0, stream>>>(bbuf, rowptr, eidx, N, E);
    sortrow_wave<<<(N * 64 + T - 1) / T, T, 0, stream>>>(rowptr, eidx, N);

    // --- layer 1: h1' = dinv * (x @ W1) -> A; aggregate+relu -> B ---
    gemm_tiled<64, 64><<<(N + 63) / 64, T, 0, stream>>>(x, W1, dinv, A, N);
    agg_kernel<64, true><<<(N * 64 + T - 1) / T, T, 0, stream>>>(eidx, rowptr, dinv, A, b1, B, N);

    // --- layer 2 ---
    gemm_tiled<64, 32><<<(N + 127) / 128, T, 0, stream>>>(B, W2, dinv, A, N);
    agg_kernel<32, true><<<(N * 32 + T - 1) / T, T, 0, stream>>>(eidx, rowptr, dinv, A, b2, B, N);

    // --- layer 3 ---
    gemm_kernel<32, 2><<<(N + 127) / 128, T, 0, stream>>>(B, W3, dinv, A, N);
    agg_kernel<2, false><<<(N * 2 + T - 1) / T, T, 0, stream>>>(eidx, rowptr, dinv, A, b3, out, N);
}

// Round 10
// 305.597 us; speedup vs baseline: 1.7191x; 1.3659x over previous
//
#include <hip/hip_runtime.h>
#include <hip/hip_fp16.h>

#define N_NODES 100000
#define N_EDGES 1600000
#define BSHIFT 9
#define NBUCK ((N_NODES + 511) / 512)   // 196 coarse buckets of 512 nodes
#define BCAP 12288                      // per-bucket capacity (mean 8163, ~45 sigma)

// ---------------------------------------------------------------------------
// phase 1: bucket edges by dst>>9 into fixed-capacity bucket regions.
// Per-block LDS hist -> one global atomicAdd per (block,bucket) reserves a
// private subrange; gbcount[b] ends up holding bucket b's size.
__global__ void bucket1_kernel(const int* __restrict__ src, const int* __restrict__ dst,
                               int* __restrict__ gbcount, int2* __restrict__ bbuf, int E) {
    __shared__ int hcnt[NBUCK];
    __shared__ int hbase[NBUCK];
    int t = threadIdx.x;
    for (int i = t; i < NBUCK; i += 256) hcnt[i] = 0;
    __syncthreads();
    int e0 = blockIdx.x * 2048 + t;
    int ss[8], dd[8];
#pragma unroll
    for (int u = 0; u < 8; u++) {
        int e = e0 + u * 256;
        if (e < E) {
            ss[u] = src[e];
            dd[u] = dst[e];
            atomicAdd(&hcnt[dd[u] >> BSHIFT], 1);
        } else {
            dd[u] = -1;
        }
    }
    __syncthreads();
    for (int i = t; i < NBUCK; i += 256) {
        int c = hcnt[i];
        hbase[i] = c ? atomicAdd(&gbcount[i], c) : 0;
        hcnt[i] = 0;   // reuse as local cursor
    }
    __syncthreads();
#pragma unroll
    for (int u = 0; u < 8; u++) {
        if (dd[u] >= 0) {
            int bk = dd[u] >> BSHIFT;
            int r = atomicAdd(&hcnt[bk], 1);
            bbuf[(size_t)bk * BCAP + hbase[bk] + r] = make_int2(ss[u], dd[u]);
        }
    }
}

// --- exclusive scan of the 196 bucket sizes -> bucket bases; rowptr[N]=E ----
__global__ void scan196_kernel(const int* __restrict__ gbcount, int* __restrict__ gbase,
                               int* __restrict__ rowptrN, int E) {
    __shared__ int s[256];
    int t = threadIdx.x;
    int v = (t < NBUCK) ? gbcount[t] : 0;
    s[t] = v;
    __syncthreads();
    for (int off = 1; off < 256; off <<= 1) {
        int u = (t >= off) ? s[t - off] : 0;
        __syncthreads();
        s[t] += u;
        __syncthreads();
    }
    if (t < NBUCK) gbase[t] = s[t] - v;
    if (t == 0) *rowptrN = E;
}

// --- phase 2 (fused hist+scan+dinv+scatter): one 512-thread block per bucket.
// LDS-histogram the bucket's 512 nodes, LDS-scan -> rowptr + dinv, then
// scatter eidx into a block-private ~32KB range (single XCD, full-line writes).
__global__ __launch_bounds__(512)
void bucket2_kernel(const int2* __restrict__ bbuf, const int* __restrict__ gbcount,
                    const int* __restrict__ gbase, int* __restrict__ rowptr,
                    float* __restrict__ dinv, int* __restrict__ eidx, int N) {
    int b = blockIdx.x;
    int base_node = b << BSHIFT;
    int nn = min(512, N - base_node);
    int t = threadIdx.x;
    __shared__ int s[512];
    __shared__ int cur[512];
    s[t] = 0;
    __syncthreads();
    int sz = gbcount[b];
    const int2* eb = bbuf + (size_t)b * BCAP;
    for (int j = t; j < sz; j += 512) atomicAdd(&s[eb[j].y - base_node], 1);
    __syncthreads();
    int myc = s[t];
    if (t < nn) dinv[base_node + t] = rsqrtf((float)myc + 1.0f);
    __syncthreads();
    for (int off = 1; off < 512; off <<= 1) {
        int u = (t >= off) ? s[t - off] : 0;
        __syncthreads();
        s[t] += u;
        __syncthreads();
    }
    int rp = gbase[b] + s[t] - myc;      // exclusive
    if (t < nn) rowptr[base_node + t] = rp;
    cur[t] = rp;
    __syncthreads();
    for (int j = t; j < sz; j += 512) {
        int2 e = eb[j];
        int pos = atomicAdd(&cur[e.y - base_node], 1);
        eidx[pos] = e.x;
    }
}

// --- determinism: canonicalize each row (sort ascending). One WAVE per row,
// bitonic via shfl_xor (deg ~Poisson(16), max << 64; serial fallback).
__global__ void sortrow_wave(const int* __restrict__ rowptr, int* __restrict__ eidx, int n) {
    int g = (blockIdx.x * blockDim.x + threadIdx.x) >> 6;
    int lane = threadIdx.x & 63;
    if (g >= n) return;
    int start = rowptr[g];
    int end = rowptr[g + 1];
    int len = end - start;
    if (len <= 1) return;

    if (len <= 64) {
        int v = (lane < len) ? eidx[start + lane] : 0x7fffffff;
#pragma unroll
        for (int k = 2; k <= 64; k <<= 1) {
#pragma unroll
            for (int j = k >> 1; j > 0; j >>= 1) {
                int partner = __shfl_xor(v, j, 64);
                bool up = ((lane & k) == 0);
                bool keepMin = (((lane & j) == 0) == up);
                int mn = min(v, partner), mx = max(v, partner);
                v = keepMin ? mn : mx;
            }
        }
        if (lane < len) eidx[start + lane] = v;
    } else if (lane == 0) {
        for (int i = start + 1; i < end; i++) {
            int key = eidx[i];
            int j = i - 1;
            while (j >= start && eidx[j] > key) { eidx[j + 1] = eidx[j]; j--; }
            eidx[j + 1] = key;
        }
    }
}

// ---------------------------------------------------------------------------
// LDS-tiled GEMM, 4x4 register blocking, epilogue scales row r by dinv[r] and
// stores as TO (fp16 for the gathered intermediates, fp32 for the last layer).
// __launch_bounds__(256,2) + unroll 2: no spill (round-4 lesson).
template <int FIN, int FOUT, typename TO>
__global__ __launch_bounds__(256, 2)
void gemm_tiled(const float* __restrict__ in, const float* __restrict__ W,
                const float* __restrict__ dinv, TO* __restrict__ out, int n) {
    constexpr int CG = FOUT / 4;
    constexpr int RG = 256 / CG;
    constexpr int TR = RG * 4;
    constexpr int LDA = FIN + 4;
    __shared__ float sIn[TR * LDA];
    __shared__ float sW[FIN * FOUT];

    for (int i = threadIdx.x; i < FIN * FOUT / 4; i += 256)
        ((float4*)sW)[i] = ((const float4*)W)[i];

    int r0 = blockIdx.x * TR;
    for (int i = threadIdx.x; i < TR * FIN / 4; i += 256) {
        int rr = i / (FIN / 4);
        int cc = i % (FIN / 4);
        int gr = r0 + rr;
        float4 v = (gr < n) ? ((const float4*)in)[(size_t)gr * (FIN / 4) + cc]
                            : make_float4(0.f, 0.f, 0.f, 0.f);
        *(float4*)&sIn[rr * LDA + cc * 4] = v;
    }
    __syncthreads();

    int tc = threadIdx.x % CG;
    int tr = threadIdx.x / CG;
    int rbase = tr * 4, cbase = tc * 4;
    float acc[4][4] = {};

#pragma unroll 2
    for (int k = 0; k < FIN; k += 4) {
        float4 a[4], b[4];
#pragma unroll
        for (int i = 0; i < 4; i++) a[i] = *(float4*)&sIn[(rbase + i) * LDA + k];
#pragma unroll
        for (int kk = 0; kk < 4; kk++) b[kk] = *(float4*)&sW[(k + kk) * FOUT + cbase];
#pragma unroll
        for (int i = 0; i < 4; i++) {
            acc[i][0] += a[i].x * b[0].x + a[i].y * b[1].x + a[i].z * b[2].x + a[i].w * b[3].x;
            acc[i][1] += a[i].x * b[0].y + a[i].y * b[1].y + a[i].z * b[2].y + a[i].w * b[3].y;
            acc[i][2] += a[i].x * b[0].z + a[i].y * b[1].z + a[i].z * b[2].z + a[i].w * b[3].z;
            acc[i][3] += a[i].x * b[0].w + a[i].y * b[1].w + a[i].z * b[2].w + a[i].w * b[3].w;
        }
    }

#pragma unroll
    for (int i = 0; i < 4; i++) {
        int gr = r0 + rbase + i;
        if (gr < n) {
            float dv = dinv[gr];
            if constexpr (sizeof(TO) == 2) {
                union { __half h[4]; uint2 u; } pk;
                pk.h[0] = __float2half_rn(dv * acc[i][0]);
                pk.h[1] = __float2half_rn(dv * acc[i][1]);
                pk.h[2] = __float2half_rn(dv * acc[i][2]);
                pk.h[3] = __float2half_rn(dv * acc[i][3]);
                *(uint2*)&out[(size_t)gr * FOUT + cbase] = pk.u;
            } else {
                *(float4*)&out[(size_t)gr * FOUT + cbase] =
                    make_float4(dv * acc[i][0], dv * acc[i][1], dv * acc[i][2], dv * acc[i][3]);
            }
        }
    }
}

// simple GEMM for the tiny 32->2 layer (fp32 out), same dinv-scaled epilogue
template <int FIN, int FOUT>
__global__ void gemm_kernel(const float* __restrict__ in, const float* __restrict__ W,
                            const float* __restrict__ dinv, float* __restrict__ out, int n) {
    __shared__ float sW[FIN * FOUT];
    for (int i = threadIdx.x; i < FIN * FOUT; i += blockDim.x) sW[i] = W[i];
    __syncthreads();
    constexpr int ROWS = 256 / FOUT;
    int r = blockIdx.x * ROWS + threadIdx.x / FOUT;
    int c = threadIdx.x % FOUT;
    if (r >= n) return;
    float acc = 0.f;
#pragma unroll
    for (int k = 0; k < FIN; k++) acc += in[r * FIN + k] * sW[k * FOUT + c];
    out[r * FOUT + c] = dinv[r] * acc;
}

// ---------------------------------------------------------------------------
// Gather-side aggregation over dinv-prescaled features h' (dtype TI):
//   out[g] = (relu?)( dinv[g] * (sum_{s in nbrs} h'[s] + h'[g]) + b )
// fp32 accumulate; zero atomics; deterministic (rows sorted); 8 chains in flight.
template <int F, bool RELU, typename TI>
__global__ void agg_kernel(const int* __restrict__ eidx, const int* __restrict__ rowptr,
                           const float* __restrict__ dinv, const TI* __restrict__ h,
                           const float* __restrict__ b, float* __restrict__ out, int n) {
    int g = (blockIdx.x * blockDim.x + threadIdx.x) / F;
    int lane = threadIdx.x % F;
    if (g >= n) return;
    int j = rowptr[g];
    int end = rowptr[g + 1];
    float di = dinv[g];
    float hs = (float)h[(size_t)g * F + lane];

    float acc0 = 0.f, acc1 = 0.f, acc2 = 0.f, acc3 = 0.f;
    float acc4 = 0.f, acc5 = 0.f, acc6 = 0.f, acc7 = 0.f;
    for (; j + 8 <= end; j += 8) {
        int s0 = eidx[j];
        int s1 = eidx[j + 1];
        int s2 = eidx[j + 2];
        int s3 = eidx[j + 3];
        int s4 = eidx[j + 4];
        int s5 = eidx[j + 5];
        int s6 = eidx[j + 6];
        int s7 = eidx[j + 7];
        acc0 += (float)h[(size_t)s0 * F + lane];
        acc1 += (float)h[(size_t)s1 * F + lane];
        acc2 += (float)h[(size_t)s2 * F + lane];
        acc3 += (float)h[(size_t)s3 * F + lane];
        acc4 += (float)h[(size_t)s4 * F + lane];
        acc5 += (float)h[(size_t)s5 * F + lane];
        acc6 += (float)h[(size_t)s6 * F + lane];
        acc7 += (float)h[(size_t)s7 * F + lane];
    }
    for (; j + 2 <= end; j += 2) {
        int s0 = eidx[j];
        int s1 = eidx[j + 1];
        acc0 += (float)h[(size_t)s0 * F + lane];
        acc1 += (float)h[(size_t)s1 * F + lane];
    }
    if (j < end) {
        acc2 += (float)h[(size_t)eidx[j] * F + lane];
    }
    float acc = ((acc0 + acc1) + (acc2 + acc3)) + ((acc4 + acc5) + (acc6 + acc7));
    float v = di * (acc + hs) + b[lane];
    out[(size_t)g * F + lane] = RELU ? fmaxf(v, 0.f) : v;
}

// ---------------------------------------------------------------------------
extern "C" void kernel_launch(void* const* d_in, const int* in_sizes, int n_in,
                              void* d_out, int out_size, void* d_ws, size_t ws_size,
                              hipStream_t stream) {
    const float* x  = (const float*)d_in[0];
    const int* ei   = (const int*)d_in[1];
    const float* W1 = (const float*)d_in[2];
    const float* b1 = (const float*)d_in[3];
    const float* W2 = (const float*)d_in[4];
    const float* b2 = (const float*)d_in[5];
    const float* W3 = (const float*)d_in[6];
    const float* b3 = (const float*)d_in[7];
    float* out = (float*)d_out;

    const int N = N_NODES;
    const int E = N_EDGES;
    const int* src = ei;
    const int* dst = ei + E;

    char* p = (char*)d_ws;
    int*   rowptr  = (int*)p;             p += ((size_t)(N + 1) * 4 + 15) / 16 * 16;
    float* dinv    = (float*)p;           p += ((size_t)N * 4 + 15) / 16 * 16;
    int*   gbcount = (int*)p;             p += ((size_t)NBUCK * 4 + 15) / 16 * 16;
    int*   gbase   = (int*)p;             p += ((size_t)NBUCK * 4 + 15) / 16 * 16;
    int*   eidx    = (int*)p;             p += (size_t)E * 4;
    __half* A      = (__half*)p;          p += (size_t)N * 64 * 2;   // fp16 gathered intermediates
    float* B       = (float*)p;                                      // fp32, also aliases bbuf
    int2*  bbuf    = (int2*)B;            // 196*12288*8 = 19.3 MB < 25.6 MB; dead before agg1
    float* A3      = (float*)A;           // layer-3 fp32 intermediate reuses A region

    const int T = 256;

    // --- build CSR + dinv: bucket (cnt) -> scan196 -> fused hist/scan/scatter ---
    hipMemsetAsync(gbcount, 0, NBUCK * sizeof(int), stream);
    bucket1_kernel<<<(E + 2047) / 2048, T, 0, stream>>>(src, dst, gbcount, bbuf, E);
    scan196_kernel<<<1, 256, 0, stream>>>(gbcount, gbase, rowptr + N, E);
    bucket2_kernel<<<NBUCK, 512, 0, stream>>>(bbuf, gbcount, gbase, rowptr, dinv, eidx, N);
    sortrow_wave<<<(N * 64 + T - 1) / T, T, 0, stream>>>(rowptr, eidx, N);

    // --- layer 1: A = fp16(dinv * (x @ W1)); aggregate+relu -> B (fp32) ---
    gemm_tiled<64, 64, __half><<<(N + 63) / 64, T, 0, stream>>>(x, W1, dinv, A, N);
    agg_kernel<64, true, __half><<<(N * 64 + T - 1) / T, T, 0, stream>>>(eidx, rowptr, dinv, A, b1, B, N);

    // --- layer 2: A = fp16(dinv * (B @ W2)); aggregate+relu -> B ---
    gemm_tiled<64, 32, __half><<<(N + 127) / 128, T, 0, stream>>>(B, W2, dinv, A, N);
    agg_kernel<32, true, __half><<<(N * 32 + T - 1) / T, T, 0, stream>>>(eidx, rowptr, dinv, A, b2, B, N);

    // --- layer 3: A3 = fp32(dinv * (B @ W3)); aggregate -> d_out ---
    gemm_kernel<32, 2><<<(N + 127) / 128, T, 0, stream>>>(B, W3, dinv, A3, N);
    agg_kernel<2, false, float><<<(N * 2 + T - 1) / T, T, 0, stream>>>(eidx, rowptr, dinv, A3, b3, out, N);
}

// Round 11
// 291.957 us; speedup vs baseline: 1.7994x; 1.0467x over previous
//
#include <hip/hip_runtime.h>
#include <hip/hip_fp16.h>

#define N_NODES 100000
#define N_EDGES 1600000
#define BSHIFT 9
#define NBUCK ((N_NODES + 511) / 512)   // 196 coarse buckets of 512 nodes
#define BCAP 12288                      // per-bucket capacity (mean 8163, ~45 sigma)

// ---------------------------------------------------------------------------
// phase 1: bucket edges by dst>>9 into fixed-capacity bucket regions.
__global__ void bucket1_kernel(const int* __restrict__ src, const int* __restrict__ dst,
                               int* __restrict__ gbcount, int2* __restrict__ bbuf, int E) {
    __shared__ int hcnt[NBUCK];
    __shared__ int hbase[NBUCK];
    int t = threadIdx.x;
    for (int i = t; i < NBUCK; i += 256) hcnt[i] = 0;
    __syncthreads();
    int e0 = blockIdx.x * 2048 + t;
    int ss[8], dd[8];
#pragma unroll
    for (int u = 0; u < 8; u++) {
        int e = e0 + u * 256;
        if (e < E) {
            ss[u] = src[e];
            dd[u] = dst[e];
            atomicAdd(&hcnt[dd[u] >> BSHIFT], 1);
        } else {
            dd[u] = -1;
        }
    }
    __syncthreads();
    for (int i = t; i < NBUCK; i += 256) {
        int c = hcnt[i];
        hbase[i] = c ? atomicAdd(&gbcount[i], c) : 0;
        hcnt[i] = 0;   // reuse as local cursor
    }
    __syncthreads();
#pragma unroll
    for (int u = 0; u < 8; u++) {
        if (dd[u] >= 0) {
            int bk = dd[u] >> BSHIFT;
            int r = atomicAdd(&hcnt[bk], 1);
            bbuf[(size_t)bk * BCAP + hbase[bk] + r] = make_int2(ss[u], dd[u]);
        }
    }
}

// --- exclusive scan of the 196 bucket sizes -> bucket bases; rowptr[N]=E ----
__global__ void scan196_kernel(const int* __restrict__ gbcount, int* __restrict__ gbase,
                               int* __restrict__ rowptrN, int E) {
    __shared__ int s[256];
    int t = threadIdx.x;
    int v = (t < NBUCK) ? gbcount[t] : 0;
    s[t] = v;
    __syncthreads();
    for (int off = 1; off < 256; off <<= 1) {
        int u = (t >= off) ? s[t - off] : 0;
        __syncthreads();
        s[t] += u;
        __syncthreads();
    }
    if (t < NBUCK) gbase[t] = s[t] - v;
    if (t == 0) *rowptrN = E;
}

// --- phase 2 (fused hist+scan+dinv+scatter): one 512-thread block per bucket.
__global__ __launch_bounds__(512)
void bucket2_kernel(const int2* __restrict__ bbuf, const int* __restrict__ gbcount,
                    const int* __restrict__ gbase, int* __restrict__ rowptr,
                    float* __restrict__ dinv, int* __restrict__ eidx, int N) {
    int b = blockIdx.x;
    int base_node = b << BSHIFT;
    int nn = min(512, N - base_node);
    int t = threadIdx.x;
    __shared__ int s[512];
    __shared__ int cur[512];
    s[t] = 0;
    __syncthreads();
    int sz = gbcount[b];
    const int2* eb = bbuf + (size_t)b * BCAP;
    for (int j = t; j < sz; j += 512) atomicAdd(&s[eb[j].y - base_node], 1);
    __syncthreads();
    int myc = s[t];
    if (t < nn) dinv[base_node + t] = rsqrtf((float)myc + 1.0f);
    __syncthreads();
    for (int off = 1; off < 512; off <<= 1) {
        int u = (t >= off) ? s[t - off] : 0;
        __syncthreads();
        s[t] += u;
        __syncthreads();
    }
    int rp = gbase[b] + s[t] - myc;      // exclusive
    if (t < nn) rowptr[base_node + t] = rp;
    cur[t] = rp;
    __syncthreads();
    for (int j = t; j < sz; j += 512) {
        int2 e = eb[j];
        int pos = atomicAdd(&cur[e.y - base_node], 1);
        eidx[pos] = e.x;
    }
}

// --- determinism: canonicalize each row (sort ascending). One WAVE per row. --
__global__ void sortrow_wave(const int* __restrict__ rowptr, int* __restrict__ eidx, int n) {
    int g = (blockIdx.x * blockDim.x + threadIdx.x) >> 6;
    int lane = threadIdx.x & 63;
    if (g >= n) return;
    int start = rowptr[g];
    int end = rowptr[g + 1];
    int len = end - start;
    if (len <= 1) return;

    if (len <= 64) {
        int v = (lane < len) ? eidx[start + lane] : 0x7fffffff;
#pragma unroll
        for (int k = 2; k <= 64; k <<= 1) {
#pragma unroll
            for (int j = k >> 1; j > 0; j >>= 1) {
                int partner = __shfl_xor(v, j, 64);
                bool up = ((lane & k) == 0);
                bool keepMin = (((lane & j) == 0) == up);
                int mn = min(v, partner), mx = max(v, partner);
                v = keepMin ? mn : mx;
            }
        }
        if (lane < len) eidx[start + lane] = v;
    } else if (lane == 0) {
        for (int i = start + 1; i < end; i++) {
            int key = eidx[i];
            int j = i - 1;
            while (j >= start && eidx[j] > key) { eidx[j + 1] = eidx[j]; j--; }
            eidx[j + 1] = key;
        }
    }
}

// ---------------------------------------------------------------------------
// LDS-tiled GEMM, 4x4 register blocking, epilogue scales row r by dinv[r];
// stores TO (fp16 for gathered intermediates). No-spill config (round-4).
template <int FIN, int FOUT, typename TO>
__global__ __launch_bounds__(256, 2)
void gemm_tiled(const float* __restrict__ in, const float* __restrict__ W,
                const float* __restrict__ dinv, TO* __restrict__ out, int n) {
    constexpr int CG = FOUT / 4;
    constexpr int RG = 256 / CG;
    constexpr int TR = RG * 4;
    constexpr int LDA = FIN + 4;
    __shared__ float sIn[TR * LDA];
    __shared__ float sW[FIN * FOUT];

    for (int i = threadIdx.x; i < FIN * FOUT / 4; i += 256)
        ((float4*)sW)[i] = ((const float4*)W)[i];

    int r0 = blockIdx.x * TR;
    for (int i = threadIdx.x; i < TR * FIN / 4; i += 256) {
        int rr = i / (FIN / 4);
        int cc = i % (FIN / 4);
        int gr = r0 + rr;
        float4 v = (gr < n) ? ((const float4*)in)[(size_t)gr * (FIN / 4) + cc]
                            : make_float4(0.f, 0.f, 0.f, 0.f);
        *(float4*)&sIn[rr * LDA + cc * 4] = v;
    }
    __syncthreads();

    int tc = threadIdx.x % CG;
    int tr = threadIdx.x / CG;
    int rbase = tr * 4, cbase = tc * 4;
    float acc[4][4] = {};

#pragma unroll 2
    for (int k = 0; k < FIN; k += 4) {
        float4 a[4], b[4];
#pragma unroll
        for (int i = 0; i < 4; i++) a[i] = *(float4*)&sIn[(rbase + i) * LDA + k];
#pragma unroll
        for (int kk = 0; kk < 4; kk++) b[kk] = *(float4*)&sW[(k + kk) * FOUT + cbase];
#pragma unroll
        for (int i = 0; i < 4; i++) {
            acc[i][0] += a[i].x * b[0].x + a[i].y * b[1].x + a[i].z * b[2].x + a[i].w * b[3].x;
            acc[i][1] += a[i].x * b[0].y + a[i].y * b[1].y + a[i].z * b[2].y + a[i].w * b[3].y;
            acc[i][2] += a[i].x * b[0].z + a[i].y * b[1].z + a[i].z * b[2].z + a[i].w * b[3].z;
            acc[i][3] += a[i].x * b[0].w + a[i].y * b[1].w + a[i].z * b[2].w + a[i].w * b[3].w;
        }
    }

#pragma unroll
    for (int i = 0; i < 4; i++) {
        int gr = r0 + rbase + i;
        if (gr < n) {
            float dv = dinv[gr];
            if constexpr (sizeof(TO) == 2) {
                union { __half h[4]; uint2 u; } pk;
                pk.h[0] = __float2half_rn(dv * acc[i][0]);
                pk.h[1] = __float2half_rn(dv * acc[i][1]);
                pk.h[2] = __float2half_rn(dv * acc[i][2]);
                pk.h[3] = __float2half_rn(dv * acc[i][3]);
                *(uint2*)&out[(size_t)gr * FOUT + cbase] = pk.u;
            } else {
                *(float4*)&out[(size_t)gr * FOUT + cbase] =
                    make_float4(dv * acc[i][0], dv * acc[i][1], dv * acc[i][2], dv * acc[i][3]);
            }
        }
    }
}

// simple GEMM for the tiny 32->2 layer (fp32 out), same dinv-scaled epilogue
template <int FIN, int FOUT>
__global__ void gemm_kernel(const float* __restrict__ in, const float* __restrict__ W,
                            const float* __restrict__ dinv, float* __restrict__ out, int n) {
    __shared__ float sW[FIN * FOUT];
    for (int i = threadIdx.x; i < FIN * FOUT; i += blockDim.x) sW[i] = W[i];
    __syncthreads();
    constexpr int ROWS = 256 / FOUT;
    int r = blockIdx.x * ROWS + threadIdx.x / FOUT;
    int c = threadIdx.x % FOUT;
    if (r >= n) return;
    float acc = 0.f;
#pragma unroll
    for (int k = 0; k < FIN; k++) acc += in[r * FIN + k] * sW[k * FOUT + c];
    out[r * FOUT + c] = dinv[r] * acc;
}

// ---------------------------------------------------------------------------
// half2-granularity gather aggregation: lane owns 2 features, so a 64-lane
// wave processes 2 nodes (F=64) / 4 nodes (F=32) PER LOAD INSTRUCTION —
// doubles in-flight gather bytes per wave on the L2-miss-latency-bound path.
//   out[g] = (relu?)( dinv[g] * (sum h'[s] + h'[g]) + b )   fp32 accumulate
template <int F, bool RELU>
__global__ void agg_h2_kernel(const int* __restrict__ eidx, const int* __restrict__ rowptr,
                              const float* __restrict__ dinv, const __half2* __restrict__ h2,
                              const float* __restrict__ b, float* __restrict__ out, int n) {
    constexpr int L = F / 2;                               // lanes per node
    int g = (blockIdx.x * blockDim.x + threadIdx.x) / L;
    int lane = threadIdx.x % L;
    if (g >= n) return;
    int j = rowptr[g];
    int end = rowptr[g + 1];
    float di = dinv[g];
    float2 hs = __half22float2(h2[(size_t)g * L + lane]);

    float2 a0 = {0, 0}, a1 = {0, 0}, a2 = {0, 0}, a3 = {0, 0};
    float2 a4 = {0, 0}, a5 = {0, 0}, a6 = {0, 0}, a7 = {0, 0};
    for (; j + 8 <= end; j += 8) {
        int s0 = eidx[j];
        int s1 = eidx[j + 1];
        int s2 = eidx[j + 2];
        int s3 = eidx[j + 3];
        int s4 = eidx[j + 4];
        int s5 = eidx[j + 5];
        int s6 = eidx[j + 6];
        int s7 = eidx[j + 7];
        float2 v0 = __half22float2(h2[(size_t)s0 * L + lane]);
        float2 v1 = __half22float2(h2[(size_t)s1 * L + lane]);
        float2 v2 = __half22float2(h2[(size_t)s2 * L + lane]);
        float2 v3 = __half22float2(h2[(size_t)s3 * L + lane]);
        float2 v4 = __half22float2(h2[(size_t)s4 * L + lane]);
        float2 v5 = __half22float2(h2[(size_t)s5 * L + lane]);
        float2 v6 = __half22float2(h2[(size_t)s6 * L + lane]);
        float2 v7 = __half22float2(h2[(size_t)s7 * L + lane]);
        a0.x += v0.x; a0.y += v0.y;
        a1.x += v1.x; a1.y += v1.y;
        a2.x += v2.x; a2.y += v2.y;
        a3.x += v3.x; a3.y += v3.y;
        a4.x += v4.x; a4.y += v4.y;
        a5.x += v5.x; a5.y += v5.y;
        a6.x += v6.x; a6.y += v6.y;
        a7.x += v7.x; a7.y += v7.y;
    }
    for (; j + 2 <= end; j += 2) {
        int s0 = eidx[j];
        int s1 = eidx[j + 1];
        float2 v0 = __half22float2(h2[(size_t)s0 * L + lane]);
        float2 v1 = __half22float2(h2[(size_t)s1 * L + lane]);
        a0.x += v0.x; a0.y += v0.y;
        a1.x += v1.x; a1.y += v1.y;
    }
    if (j < end) {
        float2 v = __half22float2(h2[(size_t)eidx[j] * L + lane]);
        a2.x += v.x; a2.y += v.y;
    }
    float ax = ((a0.x + a1.x) + (a2.x + a3.x)) + ((a4.x + a5.x) + (a6.x + a7.x));
    float ay = ((a0.y + a1.y) + (a2.y + a3.y)) + ((a4.y + a5.y) + (a6.y + a7.y));
    float vx = di * (ax + hs.x) + b[2 * lane];
    float vy = di * (ay + hs.y) + b[2 * lane + 1];
    if (RELU) { vx = fmaxf(vx, 0.f); vy = fmaxf(vy, 0.f); }
    *(float2*)&out[(size_t)g * F + 2 * lane] = make_float2(vx, vy);
}

// fp32 scalar-gather agg for the tiny last layer (F=2)
template <int F, bool RELU>
__global__ void agg_kernel(const int* __restrict__ eidx, const int* __restrict__ rowptr,
                           const float* __restrict__ dinv, const float* __restrict__ h,
                           const float* __restrict__ b, float* __restrict__ out, int n) {
    int g = (blockIdx.x * blockDim.x + threadIdx.x) / F;
    int lane = threadIdx.x % F;
    if (g >= n) return;
    int j = rowptr[g];
    int end = rowptr[g + 1];
    float di = dinv[g];
    float hs = h[(size_t)g * F + lane];

    float acc0 = 0.f, acc1 = 0.f, acc2 = 0.f, acc3 = 0.f;
    float acc4 = 0.f, acc5 = 0.f, acc6 = 0.f, acc7 = 0.f;
    for (; j + 8 <= end; j += 8) {
        int s0 = eidx[j];
        int s1 = eidx[j + 1];
        int s2 = eidx[j + 2];
        int s3 = eidx[j + 3];
        int s4 = eidx[j + 4];
        int s5 = eidx[j + 5];
        int s6 = eidx[j + 6];
        int s7 = eidx[j + 7];
        acc0 += h[(size_t)s0 * F + lane];
        acc1 += h[(size_t)s1 * F + lane];
        acc2 += h[(size_t)s2 * F + lane];
        acc3 += h[(size_t)s3 * F + lane];
        acc4 += h[(size_t)s4 * F + lane];
        acc5 += h[(size_t)s5 * F + lane];
        acc6 += h[(size_t)s6 * F + lane];
        acc7 += h[(size_t)s7 * F + lane];
    }
    for (; j + 2 <= end; j += 2) {
        int s0 = eidx[j];
        int s1 = eidx[j + 1];
        acc0 += h[(size_t)s0 * F + lane];
        acc1 += h[(size_t)s1 * F + lane];
    }
    if (j < end) {
        acc2 += h[(size_t)eidx[j] * F + lane];
    }
    float acc = ((acc0 + acc1) + (acc2 + acc3)) + ((acc4 + acc5) + (acc6 + acc7));
    float v = di * (acc + hs) + b[lane];
    out[(size_t)g * F + lane] = RELU ? fmaxf(v, 0.f) : v;
}

// ---------------------------------------------------------------------------
extern "C" void kernel_launch(void* const* d_in, const int* in_sizes, int n_in,
                              void* d_out, int out_size, void* d_ws, size_t ws_size,
                              hipStream_t stream) {
    const float* x  = (const float*)d_in[0];
    const int* ei   = (const int*)d_in[1];
    const float* W1 = (const float*)d_in[2];
    const float* b1 = (const float*)d_in[3];
    const float* W2 = (const float*)d_in[4];
    const float* b2 = (const float*)d_in[5];
    const float* W3 = (const float*)d_in[6];
    const float* b3 = (const float*)d_in[7];
    float* out = (float*)d_out;

    const int N = N_NODES;
    const int E = N_EDGES;
    const int* src = ei;
    const int* dst = ei + E;

    char* p = (char*)d_ws;
    int*   rowptr  = (int*)p;             p += ((size_t)(N + 1) * 4 + 15) / 16 * 16;
    float* dinv    = (float*)p;           p += ((size_t)N * 4 + 15) / 16 * 16;
    int*   gbcount = (int*)p;             p += ((size_t)NBUCK * 4 + 15) / 16 * 16;
    int*   gbase   = (int*)p;             p += ((size_t)NBUCK * 4 + 15) / 16 * 16;
    int*   eidx    = (int*)p;             p += (size_t)E * 4;
    __half* A      = (__half*)p;          p += (size_t)N * 64 * 2;   // fp16 gathered intermediates
    float* B       = (float*)p;                                      // fp32, also aliases bbuf
    int2*  bbuf    = (int2*)B;            // 196*12288*8 = 19.3 MB; dead before agg1
    float* A3      = (float*)A;           // layer-3 fp32 intermediate reuses A region

    const int T = 256;

    // --- build CSR + dinv: bucket (cnt) -> scan196 -> fused hist/scan/scatter ---
    hipMemsetAsync(gbcount, 0, NBUCK * sizeof(int), stream);
    bucket1_kernel<<<(E + 2047) / 2048, T, 0, stream>>>(src, dst, gbcount, bbuf, E);
    scan196_kernel<<<1, 256, 0, stream>>>(gbcount, gbase, rowptr + N, E);
    bucket2_kernel<<<NBUCK, 512, 0, stream>>>(bbuf, gbcount, gbase, rowptr, dinv, eidx, N);
    sortrow_wave<<<(N * 64 + T - 1) / T, T, 0, stream>>>(rowptr, eidx, N);

    // --- layer 1: A = fp16(dinv * (x @ W1)); aggregate+relu -> B (fp32) ---
    gemm_tiled<64, 64, __half><<<(N + 63) / 64, T, 0, stream>>>(x, W1, dinv, A, N);
    agg_h2_kernel<64, true><<<(N * 32 + T - 1) / T, T, 0, stream>>>(eidx, rowptr, dinv,
                                                                    (const __half2*)A, b1, B, N);

    // --- layer 2: A = fp16(dinv * (B @ W2)); aggregate+relu -> B ---
    gemm_tiled<64, 32, __half><<<(N + 127) / 128, T, 0, stream>>>(B, W2, dinv, A, N);
    agg_h2_kernel<32, true><<<(N * 16 + T - 1) / T, T, 0, stream>>>(eidx, rowptr, dinv,
                                                                    (const __half2*)A, b2, B, N);

    // --- layer 3: A3 = fp32(dinv * (B @ W3)); aggregate -> d_out ---
    gemm_kernel<32, 2><<<(N + 127) / 128, T, 0, stream>>>(B, W3, dinv, A3, N);
    agg_kernel<2, false><<<(N * 2 + T - 1) / T, T, 0, stream>>>(eidx, rowptr, dinv, A3, b3, out, N);
}